// Round 3
// baseline (1943.427 us; speedup 1.0000x reference)
//
#include <hip/hip_runtime.h>
#include <math.h>

#define BB 4
#define HH 8
#define LL 1024
#define DD 32
#define DIMM 256

// ---------------------------------------------------------------- projections
// xq = xh@Wq, xk = rxh@Wk, xv = xh@Wv, xvr = rxh@Wv   (all f32)
__global__ __launch_bounds__(256) void k_proj(
    const float* __restrict__ x, const float* __restrict__ rx,
    const float* __restrict__ Wq, const float* __restrict__ Wk, const float* __restrict__ Wv,
    float* __restrict__ xq, float* __restrict__ xk,
    float* __restrict__ xv, float* __restrict__ xvr) {
  __shared__ float wq[32][32], wk[32][32], wv[32][32];
  __shared__ float xs[8][32], rxs[8][32];
  int tid = threadIdx.x, bid = blockIdx.x;      // grid 4096 = B*H*(L/8)
  int chunk = bid & 127, h = (bid >> 7) & 7, b = bid >> 10;
  int t0 = chunk << 3;
  for (int i = tid; i < 1024; i += 256) {
    int r = i >> 5, c = i & 31;
    wq[r][c] = Wq[i]; wk[r][c] = Wk[i]; wv[r][c] = Wv[i];
  }
  int d = tid & 31, tl = tid >> 5;
  int t = t0 + tl;
  size_t xoff = ((size_t)b * LL + t) * DIMM + h * 32 + d;
  xs[tl][d]  = x[xoff];
  rxs[tl][d] = rx[xoff];
  __syncthreads();
  float aq = 0.f, ak = 0.f, av = 0.f, ar = 0.f;
#pragma unroll
  for (int dp = 0; dp < 32; ++dp) {
    float xv_ = xs[tl][dp], rv_ = rxs[tl][dp];
    aq += xv_ * wq[dp][d];
    ak += rv_ * wk[dp][d];
    av += xv_ * wv[dp][d];
    ar += rv_ * wv[dp][d];
  }
  size_t o = (((size_t)b * HH + h) * LL + t) * DD + d;
  xq[o] = aq; xk[o] = ak; xv[o] = av; xvr[o] = ar;
}

// ---------------------------------------------------------------- dst[row,:] = sum_t w[row,t]*src[t,:]
// w: f32 [BH, L, L]; src: f32 [BH, L, 32]; dst: f32 [BH, L, 32]
__global__ __launch_bounds__(256) void k_wmat(
    const float* __restrict__ w, const float* __restrict__ src, float* __restrict__ dst) {
  __shared__ float wr[8][1028];            // pad 1028: stride%32==4 -> conflict-free
  __shared__ float part[4][8][32];
  int tid = threadIdx.x, bid = blockIdx.x;  // grid 4096 = BH*(L/8)
  int chunk = bid & 127, bh = bid >> 7;
  int row0 = chunk << 3;
  const float4* w4 = (const float4*)(w + ((size_t)bh * LL + row0) * LL);
  for (int i = tid; i < 2048; i += 256) {
    float4 u = w4[i];
    int base = i << 2;
    int r = base >> 10, c = base & 1023;
    wr[r][c]   = u.x; wr[r][c+1] = u.y;
    wr[r][c+2] = u.z; wr[r][c+3] = u.w;
  }
  __syncthreads();
  int dq = tid & 7, r = (tid >> 3) & 7, tc = tid >> 6;
  const float4* s4 = (const float4*)(src + (size_t)bh * LL * DD);
  float4 acc = make_float4(0.f, 0.f, 0.f, 0.f);
  for (int t = tc; t < LL; t += 4) {
    float wv_ = wr[r][t];
    float4 s = s4[t * 8 + dq];
    acc.x += wv_ * s.x; acc.y += wv_ * s.y; acc.z += wv_ * s.z; acc.w += wv_ * s.w;
  }
  part[tc][r][dq*4+0] = acc.x; part[tc][r][dq*4+1] = acc.y;
  part[tc][r][dq*4+2] = acc.z; part[tc][r][dq*4+3] = acc.w;
  __syncthreads();
  int d = tid & 31, rr = (tid >> 5) & 7;
  float sum = part[0][rr][d] + part[1][rr][d] + part[2][rr][d] + part[3][rr][d];
  dst[((size_t)bh * LL + row0 + rr) * DD + d] = sum;
}

// ---------------------------------------------------------------- S = qk^T, lrelu, R-mix, mask, softmax -> A (f32)
__global__ __launch_bounds__(256) void k_attn(
    const float* __restrict__ q, const float* __restrict__ k,
    const float* __restrict__ Rm, const float* __restrict__ adj,
    float* __restrict__ A) {
  __shared__ float S[8][1024];
  __shared__ float qrow[8][32];
  __shared__ float Rl[8][8];
  int tid = threadIdx.x, bid = blockIdx.x;   // grid 4096 = B*L
  int l = bid & 1023, b = bid >> 10;
  if (tid < 64) Rl[tid >> 3][tid & 7] = Rm[tid];
  {
    int h0 = tid >> 5, d0 = tid & 31;
    qrow[h0][d0] = q[(((size_t)b * HH + h0) * LL + l) * DD + d0];
  }
  __syncthreads();
  int h = tid >> 5, tl = tid & 31;
  float qr[32];
#pragma unroll
  for (int i = 0; i < 32; ++i) qr[i] = qrow[h][i];
  const float4* k4 = (const float4*)(k + ((size_t)b * HH + h) * LL * DD);
  for (int tt = 0; tt < 32; ++tt) {
    int t = (tt << 5) + tl;
    float acc = 0.f;
#pragma unroll
    for (int i = 0; i < 8; ++i) {
      float4 kv = k4[t * 8 + i];
      acc += qr[4*i] * kv.x + qr[4*i+1] * kv.y + qr[4*i+2] * kv.z + qr[4*i+3] * kv.w;
    }
    S[h][t] = acc * 0.0625f;   // scale = DIM**-0.5 = 1/16
  }
  __syncthreads();
  // phase B: this 32-lane group owns output head i = h
  float rr_[8];
#pragma unroll
  for (int j = 0; j < 8; ++j) rr_[j] = Rl[h][j];
  const float* arow = adj + (((size_t)b * HH + h) * LL + l) * LL;
  float m[32];
#pragma unroll
  for (int tt = 0; tt < 32; ++tt) {
    int t = (tt << 5) + tl;
    float acc = 0.f;
#pragma unroll
    for (int j = 0; j < 8; ++j) {
      float s = S[j][t];
      s = (s > 0.f) ? s : 0.01f * s;   // leaky_relu before mixing
      acc += rr_[j] * s;
    }
    float a = arow[t];
    m[tt] = (a > 0.f) ? acc : -INFINITY;
  }
  float mx = -INFINITY;
#pragma unroll
  for (int tt = 0; tt < 32; ++tt) mx = fmaxf(mx, m[tt]);
#pragma unroll
  for (int o = 16; o > 0; o >>= 1) mx = fmaxf(mx, __shfl_xor(mx, o, 32));
  float sm = 0.f;
#pragma unroll
  for (int tt = 0; tt < 32; ++tt) { m[tt] = expf(m[tt] - mx); sm += m[tt]; }
#pragma unroll
  for (int o = 16; o > 0; o >>= 1) sm += __shfl_xor(sm, o, 32);
  float inv = 1.0f / sm;
  float* Arow = A + (((size_t)b * HH + h) * LL + l) * LL;
#pragma unroll
  for (int tt = 0; tt < 32; ++tt) {
    int t = (tt << 5) + tl;
    Arow[t] = m[tt] * inv;
  }
}

// ---------------------------------------------------------------- colsum partials: sum_l exp(A[l,t]) over 32-row chunks
__global__ __launch_bounds__(256) void k_colpart(
    const float* __restrict__ A, float* __restrict__ colpart) {
  int tid = threadIdx.x, bid = blockIdx.x;   // grid 1024 = BH*32
  int chunk = bid & 31, bh = bid >> 5;
  int l0 = chunk << 5;
  const float4* A4 = (const float4*)(A + ((size_t)bh * LL + l0) * LL);
  float a0 = 0.f, a1 = 0.f, a2 = 0.f, a3 = 0.f;
  for (int lr = 0; lr < 32; ++lr) {
    float4 u = A4[lr * 256 + tid];
    a0 += __expf(u.x); a1 += __expf(u.y); a2 += __expf(u.z); a3 += __expf(u.w);
  }
  float4* cp = (float4*)(colpart + ((size_t)bh * 32 + chunk) * LL);
  cp[tid] = make_float4(a0, a1, a2, a3);
}

__global__ __launch_bounds__(256) void k_colred(
    const float* __restrict__ colpart, float* __restrict__ colsum) {
  int gid = blockIdx.x * 256 + threadIdx.x;  // 32768 = BH*L
  int bh = gid >> 10, t = gid & 1023;
  const float* cp = colpart + (size_t)bh * 32 * LL + t;
  float s = 0.f;
#pragma unroll
  for (int c = 0; c < 32; ++c) s += cp[c * LL];
  colsum[gid] = s;
}

// ---------------------------------------------------------------- Ar[t,l] = exp(A[l,t]) / colsum[t]  (64x64 LDS transpose)
__global__ __launch_bounds__(256) void k_ar(
    const float* __restrict__ A, const float* __restrict__ colsum, float* __restrict__ Ar) {
  __shared__ float tile[64][65];
  int tid = threadIdx.x, bid = blockIdx.x;   // grid 8192 = BH*16*16
  int tix = bid & 15, tiy = (bid >> 4) & 15, bh = bid >> 8;
  int l0 = tiy << 6, t0 = tix << 6;
  int c = tid & 63, r4 = tid >> 6;
  const float* Ab = A + ((size_t)bh * LL + l0) * LL + t0;
#pragma unroll
  for (int rr = 0; rr < 16; ++rr) {
    int li = (rr << 2) + r4;
    tile[li][c] = expf(Ab[(size_t)li * LL + c]);
  }
  __syncthreads();
  float* Arb = Ar + ((size_t)bh * LL + t0) * LL + l0;
  const float* cs = colsum + bh * LL + t0;
#pragma unroll
  for (int rr = 0; rr < 16; ++rr) {
    int ti = (rr << 2) + r4;
    float inv = 1.0f / cs[ti];
    Arb[(size_t)ti * LL + c] = tile[c][ti] * inv;
  }
}

// ---------------------------------------------------------------- out = gelu(v_merged) @ Wp  (f32 out)
__global__ __launch_bounds__(256) void k_out(
    const float* __restrict__ vbuf, const float* __restrict__ Wp, float* __restrict__ out) {
  __shared__ float g[256];
  int tid = threadIdx.x, bid = blockIdx.x;   // grid 4096 = B*L
  int l = bid & 1023, b = bid >> 10;
  int h = tid >> 5, d = tid & 31;
  float v = vbuf[(((size_t)b * HH + h) * LL + l) * DD + d];
  g[tid] = 0.5f * v * (1.0f + erff(v * 0.70710678118654752f));  // exact gelu
  __syncthreads();
  float acc = 0.f;
  for (int j = 0; j < 256; ++j) acc += g[j] * Wp[j * 256 + tid];
  out[((size_t)b * LL + l) * DIMM + tid] = acc;
}

extern "C" void kernel_launch(void* const* d_in, const int* in_sizes, int n_in,
                              void* d_out, int out_size, void* d_ws, size_t ws_size,
                              hipStream_t stream) {
  const float* x    = (const float*)d_in[0];
  const float* rx   = (const float*)d_in[1];
  const float* adj  = (const float*)d_in[2];
  const float* adjr = (const float*)d_in[3];
  const float* Wq   = (const float*)d_in[4];
  const float* Wk   = (const float*)d_in[5];
  const float* Wv   = (const float*)d_in[6];
  const float* Rm   = (const float*)d_in[7];
  const float* Wp   = (const float*)d_in[8];

  const size_t NE = (size_t)BB * HH * LL * DD;   // 1,048,576

  float* out  = (float*)d_out;
  float* outr = out + (size_t)BB * LL * DIMM;
  float* A    = outr + (size_t)BB * LL * DIMM;
  float* Ar   = A + (size_t)BB * HH * LL * LL;

  // f32 scratch overlaid on the Ar region of d_out (dead until k_ar, which
  // rewrites every element). Region = 33.5M floats; we use 5M.
  float* xq      = Ar;
  float* xk      = Ar + 1 * NE;
  float* q       = Ar + 2 * NE;
  float* k       = Ar + 3 * NE;
  float* colpart = Ar + 4 * NE;

  // d_ws: 12.2 MB used
  float* wsf    = (float*)d_ws;
  float* xv     = wsf;                 // 1M f32
  float* xvr    = wsf + 1 * NE;        // 1M f32
  float* vb     = wsf + 2 * NE;        // 1M f32 (reused for vr)
  float* colsum = wsf + 3 * NE;        // 32768 f32

  k_proj<<<4096, 256, 0, stream>>>(x, rx, Wq, Wk, Wv, xq, xk, xv, xvr);
  k_wmat<<<4096, 256, 0, stream>>>(adj,  xq, q);
  k_wmat<<<4096, 256, 0, stream>>>(adjr, xk, k);
  k_attn<<<4096, 256, 0, stream>>>(q, k, Rm, adj, A);
  k_colpart<<<1024, 256, 0, stream>>>(A, colpart);
  k_colred<<<128, 256, 0, stream>>>(colpart, colsum);
  k_ar<<<8192, 256, 0, stream>>>(A, colsum, Ar);      // overwrites all Ar-region scratch
  k_wmat<<<4096, 256, 0, stream>>>(A,  xv,  vb);
  k_out<<<4096, 256, 0, stream>>>(vb, Wp, out);
  k_wmat<<<4096, 256, 0, stream>>>(Ar, xvr, vb);      // reuse vb
  k_out<<<4096, 256, 0, stream>>>(vb, Wp, outr);
}

// Round 4
// 864.014 us; speedup vs baseline: 2.2493x; 2.2493x over previous
//
#include <hip/hip_runtime.h>
#include <math.h>

#define BB 4
#define HH 8
#define LL 1024
#define DD 32
#define DIMM 256

// ---------------------------------------------------------------- projections
// xq = xh@Wq, xk = rxh@Wk, xv = xh@Wv, xvr = rxh@Wv   (all f32)
__global__ __launch_bounds__(256) void k_proj(
    const float* __restrict__ x, const float* __restrict__ rx,
    const float* __restrict__ Wq, const float* __restrict__ Wk, const float* __restrict__ Wv,
    float* __restrict__ xq, float* __restrict__ xk,
    float* __restrict__ xv, float* __restrict__ xvr) {
  __shared__ float wq[32][32], wk[32][32], wv[32][32];
  __shared__ float xs[8][32], rxs[8][32];
  int tid = threadIdx.x, bid = blockIdx.x;      // grid 4096 = B*H*(L/8)
  int chunk = bid & 127, h = (bid >> 7) & 7, b = bid >> 10;
  int t0 = chunk << 3;
  for (int i = tid; i < 1024; i += 256) {
    int r = i >> 5, c = i & 31;
    wq[r][c] = Wq[i]; wk[r][c] = Wk[i]; wv[r][c] = Wv[i];
  }
  int d = tid & 31, tl = tid >> 5;
  int t = t0 + tl;
  size_t xoff = ((size_t)b * LL + t) * DIMM + h * 32 + d;
  xs[tl][d]  = x[xoff];
  rxs[tl][d] = rx[xoff];
  __syncthreads();
  float aq = 0.f, ak = 0.f, av = 0.f, ar = 0.f;
#pragma unroll
  for (int dp = 0; dp < 32; ++dp) {
    float xv_ = xs[tl][dp], rv_ = rxs[tl][dp];
    aq += xv_ * wq[dp][d];
    ak += rv_ * wk[dp][d];
    av += xv_ * wv[dp][d];
    ar += rv_ * wv[dp][d];
  }
  size_t o = (((size_t)b * HH + h) * LL + t) * DD + d;
  xq[o] = aq; xk[o] = ak; xv[o] = av; xvr[o] = ar;
}

// ---------------------------------------------------------------- dst[row,:] = sum_t w[row,t]*src[t,:]
// 32 rows/block, t-chunks of 256, w + transposed src in LDS.
__global__ __launch_bounds__(256) void k_wmat(
    const float* __restrict__ w, const float* __restrict__ src, float* __restrict__ dst) {
  __shared__ float w_s[32 * 260];   // [r][t] stride 260 (b128-aligned, low-conflict)
  __shared__ float sT[32 * 258];    // [d][t] stride 258 (b64 reads, 2-way max)
  int tid = threadIdx.x, bid = blockIdx.x;  // grid 1024 = BH * (L/32)
  int ch = bid & 31, bh = bid >> 5;
  int row0 = ch << 5;
  int d = tid & 31, rq = tid >> 5;          // rq in 0..7, rows rq+8j
  float acc[4] = {0.f, 0.f, 0.f, 0.f};
  const float* wbase = w + ((size_t)bh * LL + row0) * LL;
  const float* sbase = src + (size_t)bh * LL * DD;
  for (int cc = 0; cc < 4; ++cc) {
    int t0 = cc << 8;
    {
      int r = tid >> 3, c4 = tid & 7;
#pragma unroll
      for (int u = 0; u < 8; ++u) {
        int col = (c4 << 2) + (u << 5);
        float4 v = *(const float4*)(wbase + (size_t)r * LL + t0 + col);
        *(float4*)&w_s[r * 260 + col] = v;
      }
    }
#pragma unroll
    for (int jj = 0; jj < 8; ++jj) {
      int idx = tid + (jj << 8);       // 0..2047
      int t = idx >> 3, d4 = idx & 7;
      float4 v = *(const float4*)(sbase + (size_t)(t0 + t) * DD + (d4 << 2));
      int ddd = d4 << 2;
      sT[(ddd + 0) * 258 + t] = v.x;
      sT[(ddd + 1) * 258 + t] = v.y;
      sT[(ddd + 2) * 258 + t] = v.z;
      sT[(ddd + 3) * 258 + t] = v.w;
    }
    __syncthreads();
    const float* sp = &sT[d * 258];
#pragma unroll 4
    for (int t2 = 0; t2 < 128; ++t2) {
      float2 s2 = *(const float2*)(sp + (t2 << 1));
#pragma unroll
      for (int j = 0; j < 4; ++j) {
        float2 w2 = *(const float2*)&w_s[(rq + (j << 3)) * 260 + (t2 << 1)];
        acc[j] += w2.x * s2.x + w2.y * s2.y;
      }
    }
    __syncthreads();
  }
#pragma unroll
  for (int j = 0; j < 4; ++j)
    dst[((size_t)bh * LL + row0 + rq + (j << 3)) * DD + d] = acc[j];
}

// ---------------------------------------------------------------- logits: S=qk^T/16, lrelu, R-mix, mask
// writes masked mixed logits M (A region) + per-row running max / inv-sum
__global__ __launch_bounds__(256) void k_logits(
    const float* __restrict__ q, const float* __restrict__ k,
    const float* __restrict__ Rm, const float* __restrict__ adj,
    float* __restrict__ M, float* __restrict__ mxb, float* __restrict__ invb) {
  __shared__ float k_s[8 * 2178];          // [h] stride 2178 = 64*34+2; [t] stride 34
  __shared__ float S_s[128 * 66];          // [(h*16+r)] stride 66
  __shared__ float mstat[8][16];
  __shared__ float sstat[8][16];
  int tid = threadIdx.x, bid = blockIdx.x;   // grid 256 = b(4) x lt(64)
  int lt = bid & 63, b = bid >> 6;
  int l0 = lt << 4;
  int h  = tid >> 5;          // S-phase head; also mix-phase output head i
  int rp = (tid >> 2) & 7;
  int tq = tid & 3;
  int tl = tid & 31;
  if (tid < 128) { mstat[tid >> 4][tid & 15] = -INFINITY; sstat[tid >> 4][tid & 15] = 0.f; }
  // q rows 2rp, 2rp+1 of head h -> registers
  float q0[32], q1[32];
  {
    const float* qp0 = q + (((size_t)b * HH + h) * LL + l0 + 2 * rp) * DD;
#pragma unroll
    for (int i = 0; i < 8; ++i) {
      float4 a = ((const float4*)qp0)[i];
      float4 c = ((const float4*)(qp0 + DD))[i];
      q0[4*i] = a.x; q0[4*i+1] = a.y; q0[4*i+2] = a.z; q0[4*i+3] = a.w;
      q1[4*i] = c.x; q1[4*i+1] = c.y; q1[4*i+2] = c.z; q1[4*i+3] = c.w;
    }
  }
  float r8[8];
#pragma unroll
  for (int j = 0; j < 8; ++j) r8[j] = Rm[h * 8 + j];
  __syncthreads();
  for (int cc = 0; cc < 16; ++cc) {
    int t0 = cc << 6;
    // stage K chunk (all 8 heads, 64 t)
#pragma unroll
    for (int jj = 0; jj < 16; ++jj) {
      int idx = tid + (jj << 8);        // 0..4095 float4 ids
      int hh = idx >> 9, rem = idx & 511;
      int t = rem >> 3, d4 = rem & 7;
      float4 v = *(const float4*)(k + (((size_t)b * HH + hh) * LL + t0 + t) * DD + (d4 << 2));
      float* dstp = &k_s[hh * 2178 + t * 34 + (d4 << 2)];
      dstp[0] = v.x; dstp[1] = v.y; dstp[2] = v.z; dstp[3] = v.w;
    }
    __syncthreads();                       // k_s ready; prev mix done
    // S-phase
    {
      const float* kbase = &k_s[h * 2178];
#pragma unroll 2
      for (int tt = 0; tt < 16; ++tt) {
        int t = (tt << 2) + tq;
        const float* kr = kbase + t * 34;
        float a0 = 0.f, a1 = 0.f;
#pragma unroll
        for (int j = 0; j < 16; ++j) {
          float2 kv = *(const float2*)(kr + 2 * j);
          a0 += q0[2*j] * kv.x + q0[2*j+1] * kv.y;
          a1 += q1[2*j] * kv.x + q1[2*j+1] * kv.y;
        }
        S_s[(h * 16 + 2 * rp) * 66 + t]     = a0 * 0.0625f;
        S_s[(h * 16 + 2 * rp + 1) * 66 + t] = a1 * 0.0625f;
      }
    }
    __syncthreads();                       // S_s ready
    // mix phase: output head i = h, t in {tl, tl+32}
    for (int r = 0; r < 16; ++r) {
      float m0 = 0.f, m1 = 0.f;
#pragma unroll
      for (int j = 0; j < 8; ++j) {
        float s0 = S_s[(j * 16 + r) * 66 + tl];
        float s1 = S_s[(j * 16 + r) * 66 + tl + 32];
        s0 = (s0 > 0.f) ? s0 : 0.01f * s0;
        s1 = (s1 > 0.f) ? s1 : 0.01f * s1;
        m0 += r8[j] * s0; m1 += r8[j] * s1;
      }
      size_t rowoff = (((size_t)b * HH + h) * LL + l0 + r) * LL + t0;
      float a0v = adj[rowoff + tl], a1v = adj[rowoff + tl + 32];
      if (a0v <= 0.f) m0 = -INFINITY;
      if (a1v <= 0.f) m1 = -INFINITY;
      M[rowoff + tl] = m0; M[rowoff + tl + 32] = m1;
      float cm = fmaxf(m0, m1);
#pragma unroll
      for (int o = 16; o > 0; o >>= 1) cm = fmaxf(cm, __shfl_xor(cm, o, 32));
      float mold = mstat[h][r];
      float nm = fmaxf(mold, cm);
      if (nm != -INFINITY) {
        float e = __expf(m0 - nm) + __expf(m1 - nm);   // exp(-inf)=0
#pragma unroll
        for (int o = 16; o > 0; o >>= 1) e += __shfl_xor(e, o, 32);
        if (tl == 0) {
          float sc = (mold == -INFINITY) ? 0.f : __expf(mold - nm);
          sstat[h][r] = sstat[h][r] * sc + e;
          mstat[h][r] = nm;
        }
      }
    }
  }
  __syncthreads();
  if (tid < 128) {
    int i = tid >> 4, r = tid & 15;
    size_t o = ((size_t)b * HH + i) * LL + l0 + r;
    mxb[o] = mstat[i][r];
    invb[o] = 1.0f / sstat[i][r];
  }
}

// ---------------------------------------------------------------- normalize M->A in place + column partials of exp(A)
__global__ __launch_bounds__(256) void k_norm(
    float* __restrict__ A, const float* __restrict__ mxb, const float* __restrict__ invb,
    float* __restrict__ colpart) {
  int tid = threadIdx.x, bid = blockIdx.x;   // grid 1024 = bh(32) x ch(32)
  int ch = bid & 31, bh = bid >> 5;
  int l0 = ch << 5;
  float4 cp = make_float4(0.f, 0.f, 0.f, 0.f);
  for (int rr = 0; rr < 32; ++rr) {
    int l = l0 + rr;
    float mx  = mxb[(size_t)bh * LL + l];
    float inv = invb[(size_t)bh * LL + l];
    float4* Ap = (float4*)(A + ((size_t)bh * LL + l) * LL) + tid;
    float4 m4 = *Ap;
    float4 a4;
    a4.x = __expf(m4.x - mx) * inv;
    a4.y = __expf(m4.y - mx) * inv;
    a4.z = __expf(m4.z - mx) * inv;
    a4.w = __expf(m4.w - mx) * inv;
    *Ap = a4;
    cp.x += __expf(a4.x); cp.y += __expf(a4.y);
    cp.z += __expf(a4.z); cp.w += __expf(a4.w);
  }
  ((float4*)(colpart + ((size_t)bh * 32 + ch) * LL))[tid] = cp;
}

__global__ __launch_bounds__(256) void k_colred(
    const float* __restrict__ colpart, float* __restrict__ colsum) {
  int gid = blockIdx.x * 256 + threadIdx.x;  // 32768 = BH*L
  int bh = gid >> 10, t = gid & 1023;
  const float* cp = colpart + (size_t)bh * 32 * LL + t;
  float s = 0.f;
#pragma unroll
  for (int c = 0; c < 32; ++c) s += cp[c * LL];
  colsum[gid] = s;
}

// ---------------------------------------------------------------- Ar[t,l] = exp(A[l,t]) / colsum[t]
__global__ __launch_bounds__(256) void k_ar(
    const float* __restrict__ A, const float* __restrict__ colsum, float* __restrict__ Ar) {
  __shared__ float tile[64][65];
  int tid = threadIdx.x, bid = blockIdx.x;   // grid 8192 = BH*16*16
  int tix = bid & 15, tiy = (bid >> 4) & 15, bh = bid >> 8;
  int l0 = tiy << 6, t0 = tix << 6;
  int c = tid & 63, r4 = tid >> 6;
  const float* Ab = A + ((size_t)bh * LL + l0) * LL + t0;
#pragma unroll
  for (int rr = 0; rr < 16; ++rr) {
    int li = (rr << 2) + r4;
    tile[li][c] = __expf(Ab[(size_t)li * LL + c]);
  }
  __syncthreads();
  float* Arb = Ar + ((size_t)bh * LL + t0) * LL + l0;
  const float* cs = colsum + bh * LL + t0;
#pragma unroll
  for (int rr = 0; rr < 16; ++rr) {
    int ti = (rr << 2) + r4;
    float inv = 1.0f / cs[ti];
    Arb[(size_t)ti * LL + c] = tile[c][ti] * inv;
  }
}

// ---------------------------------------------------------------- out = gelu(v_merged) @ Wp, 16 rows/block
__global__ __launch_bounds__(256) void k_out(
    const float* __restrict__ vbuf, const float* __restrict__ Wp, float* __restrict__ out) {
  __shared__ float g_s[16 * 256];
  __shared__ float wp_s[32 * 256];
  int tid = threadIdx.x, bid = blockIdx.x;   // grid 256 = b(4) x lt(64)
  int lt = bid & 63, b = bid >> 6;
  int l0 = lt << 4;
  int h = tid >> 5, dd = tid & 31;
#pragma unroll
  for (int r = 0; r < 16; ++r) {
    float v = vbuf[(((size_t)b * HH + h) * LL + l0 + r) * DD + dd];
    g_s[r * 256 + tid] = 0.5f * v * (1.0f + erff(v * 0.70710678118654752f));
  }
  float acc[16];
#pragma unroll
  for (int r = 0; r < 16; ++r) acc[r] = 0.f;
  for (int jc = 0; jc < 8; ++jc) {
    __syncthreads();   // g_s ready (first iter) / done reading wp_s (later)
#pragma unroll
    for (int u = 0; u < 8; ++u) {
      int idx = tid + (u << 8);      // 0..2047 float4 ids
      int j = idx >> 6, c4 = idx & 63;
      float4 v = *(const float4*)(Wp + (size_t)(jc * 32 + j) * DIMM + (c4 << 2));
      *(float4*)&wp_s[j * 256 + (c4 << 2)] = v;
    }
    __syncthreads();
#pragma unroll
    for (int j = 0; j < 32; ++j) {
      float wv = wp_s[j * 256 + tid];
      int jj = (jc << 5) + j;
#pragma unroll
      for (int r = 0; r < 16; ++r)
        acc[r] += g_s[r * 256 + jj] * wv;
    }
  }
#pragma unroll
  for (int r = 0; r < 16; ++r)
    out[((size_t)b * LL + l0 + r) * DIMM + tid] = acc[r];
}

extern "C" void kernel_launch(void* const* d_in, const int* in_sizes, int n_in,
                              void* d_out, int out_size, void* d_ws, size_t ws_size,
                              hipStream_t stream) {
  const float* x    = (const float*)d_in[0];
  const float* rx   = (const float*)d_in[1];
  const float* adj  = (const float*)d_in[2];
  const float* adjr = (const float*)d_in[3];
  const float* Wq   = (const float*)d_in[4];
  const float* Wk   = (const float*)d_in[5];
  const float* Wv   = (const float*)d_in[6];
  const float* Rm   = (const float*)d_in[7];
  const float* Wp   = (const float*)d_in[8];

  const size_t NE = (size_t)BB * HH * LL * DD;   // 1,048,576 (= B*L*DIM)

  float* out  = (float*)d_out;
  float* outr = out + NE;
  float* A    = outr + NE;
  float* Ar   = A + (size_t)BB * HH * LL * LL;

  // scratch overlaid on dead output regions:
  //  Ar region (33.5M f): xq,xk,q,k,colpart — all dead before k_ar rewrites it
  //  out region: xv (dead until k_out writes out) ; outr region: xvr
  float* xq      = Ar;
  float* xk      = Ar + 1 * NE;
  float* q       = Ar + 2 * NE;
  float* k       = Ar + 3 * NE;
  float* colpart = Ar + 4 * NE;
  float* xv      = out;
  float* xvr     = outr;

  // d_ws: 4.4 MB
  float* wsf    = (float*)d_ws;
  float* vb     = wsf;                       // 1M f32
  float* colsum = wsf + NE;                  // 32K
  float* mxb    = wsf + NE + 32768;          // 32K
  float* invb   = wsf + NE + 65536;          // 32K

  k_proj<<<4096, 256, 0, stream>>>(x, rx, Wq, Wk, Wv, xq, xk, xv, xvr);
  k_wmat<<<1024, 256, 0, stream>>>(adj,  xq, q);
  k_wmat<<<1024, 256, 0, stream>>>(adjr, xk, k);
  k_logits<<<256, 256, 0, stream>>>(q, k, Rm, adj, A, mxb, invb);
  k_norm<<<1024, 256, 0, stream>>>(A, mxb, invb, colpart);
  k_colred<<<128, 256, 0, stream>>>(colpart, colsum);
  k_ar<<<8192, 256, 0, stream>>>(A, colsum, Ar);      // overwrites Ar-region scratch
  k_wmat<<<1024, 256, 0, stream>>>(A,  xv,  vb);
  k_out<<<256, 256, 0, stream>>>(vb, Wp, out);        // out overwrites xv (already consumed)
  k_wmat<<<1024, 256, 0, stream>>>(Ar, xvr, vb);
  k_out<<<256, 256, 0, stream>>>(vb, Wp, outr);
}